// Round 15
// baseline (487.982 us; speedup 1.0000x reference)
//
#include <hip/hip_runtime.h>

typedef unsigned short u16;
typedef unsigned int   u32;

#define N_NODES    15000
#define PADN       15008
#define N_EDGES    30000
#define NUM_GRAPHS 600
#define N_STEMS    6000
#define N_JBONDS   3000

#define OUT_FINAL  0
#define OUT_STEM   1200
#define OUT_JB     631200

#define A1S 68                // a1b (global) row stride u16
#define N_CVT 26

// ---- edge-GEMM geometry (v16: EBLK=64, LDS-dedup gather; unchanged from R13) ----
#define EBLK 64               // edges per block (4 MFMA tiles)
#define EGRIDE 469            // ceil(30000/64)
#define KCH 130               // K chunks of 32 (K = 65*64 = 4160)
#define A1LS 66               // a1l row stride u16
#define RS   66               // red row stride f32
#define O2W 10                // o2l row stride in uint4

// ---- k_node v12 (persistent, LDS-resident weights) ----
#define NGROUPS (PADN/16)     // 938 groups of 16 nodes
#define NWTILES 28            // root 0-3, wih 4-15, whh 16-27
#define HS 72                 // LDS staging row stride u16
#define NODEGRID 256          // 1 block/CU (LDS-capped), stride over 938 groups

// ---- fused pack kernel segments ----
#define PACK_W2B_N (KCH*2048)        // 266240
#define PACK_NW_N  (NWTILES*4*512)   // 57344
#define PACK_HD_N  1792
#define PACK_TOTAL (PACK_W2B_N + PACK_NW_N + PACK_HD_N)   // 325376 = 1271*256

typedef short frag8 __attribute__((ext_vector_type(8)));   // 8 f16 (4 VGPRs)
typedef float facc4 __attribute__((ext_vector_type(4)));   // 4 f32 acc
typedef _Float16 h16x2 __attribute__((ext_vector_type(2)));

__device__ __forceinline__ float u2f(u16 v){ union{u32 i; float f;} c; c.i=((u32)v)<<16; return c.f; }
__device__ __forceinline__ u16  f2b(float f){ union{float f; u32 u;} c; c.f=f; u32 u=c.u;
                                              return (u16)((u + 0x7fffu + ((u>>16)&1u))>>16); }
__device__ __forceinline__ u16  f2h(float f){ union{_Float16 h; u16 u;} c; c.h = (_Float16)f; return c.u; }
__device__ __forceinline__ float h2f(u16 v){ union{u16 u; _Float16 h;} c; c.u = v; return (float)c.h; }
__device__ __forceinline__ float lrelu(float x){ return x>0.f ? x : 0.01f*x; }
__device__ __forceinline__ float sigmoidf(float x){ return 1.f/(1.f+expf(-x)); }

__device__ __forceinline__ int lower_bound_i(const int* __restrict__ a, int n, int v){
  int lo=0, hi=n;
  while(lo<hi){ int m=(lo+hi)>>1; if(a[m]<v) lo=m+1; else hi=m; }
  return lo;
}

__device__ __forceinline__ void store_out(void* dout, int isf, int idx, float v){
  if(isf) ((float*)dout)[idx] = v;
  else    ((u16*)dout)[idx]   = f2b(v);
}

// fp16 A-fragment: 4x v_pk_mul_f16
__device__ __forceinline__ frag8 pack4h(uint4 v, u32 av2){
  union { u32 d[4]; frag8 f; } au;
  h16x2 a; { union{u32 u; h16x2 h;} c; c.u = av2; a = c.h; }
  { union{u32 u; h16x2 h;} c; c.u = v.x; c.h = a * c.h; au.d[0] = c.u; }
  { union{u32 u; h16x2 h;} c; c.u = v.y; c.h = a * c.h; au.d[1] = c.u; }
  { union{u32 u; h16x2 h;} c; c.u = v.z; c.h = a * c.h; au.d[2] = c.u; }
  { union{u32 u; h16x2 h;} c; c.u = v.w; c.h = a * c.h; au.d[3] = c.u; }
  return au.f;
}

// ---------------- dtype sniff + workspace zero-init ----------------
__global__ __launch_bounds__(256) void k_sniff(const u16* __restrict__ x, int n, int* __restrict__ flag,
                                               float* __restrict__ deg, float* __restrict__ agg,
                                               float* __restrict__ outF, u16* __restrict__ outB){
  int tid = blockIdx.x*256 + threadIdx.x;
  int stride = gridDim.x*256;
  int local = 0;
  for(int i = tid; i < n; i += stride){
    u16 v = x[i];
    if(((v>>7)&0xFFu) == 0xFFu) local = 1;
  }
  if(local) atomicOr(flag, 1);
  float4 z = (float4){0.f,0.f,0.f,0.f};
  for(int i = tid; i < PADN; i += stride) deg[i] = 0.f;
  for(int i = tid; i < PADN*64/4; i += stride) ((float4*)agg)[i] = z;
  for(int i = tid; i < (PADN-N_NODES)*64/4; i += stride) ((float4*)(outF + (size_t)N_NODES*64))[i] = z;
  for(int i = tid; i < (PADN-N_NODES)*64/8; i += stride) ((float4*)(outB + (size_t)N_NODES*64))[i] = z;
}

// ---------------- convert float inputs to f32 ----------------
struct CvtArgs { const void* src[N_CVT]; float* dst[N_CVT]; int n[N_CVT]; };

__global__ __launch_bounds__(256) void k_cvt(CvtArgs A, const int* __restrict__ flag){
  int isf = *flag;
  int tid = blockIdx.x*256 + threadIdx.x;
  int stride = gridDim.x*256;
  for(int b=0; b<N_CVT; b++){
    int n = A.n[b];
    const float* sf = (const float*)A.src[b];
    const u16*   sb = (const u16*)A.src[b];
    float* d = A.dst[b];
    for(int i=tid; i<n; i+=stride) d[i] = isf ? sf[i] : u2f(sb[i]);
  }
}

// ---------------- lin0 (writes f32 out + fp16 mirror) ----------------
__global__ __launch_bounds__(64) void k_lin0(const float* __restrict__ x, const float* __restrict__ w,
                                             const float* __restrict__ b,
                                             float* __restrict__ outF, u16* __restrict__ outB){
  int n = blockIdx.x, o = threadIdx.x;
  __shared__ float xs[14];
  if(o<14) xs[o] = x[n*14+o];
  __syncthreads();
  float acc = b[o];
  #pragma unroll
  for(int i=0;i<14;i++) acc += xs[i]*w[o*14+i];
  float v = lrelu(acc);
  outF[n*64+o] = v;
  outB[n*64+o] = f2h(v);
}

// ---------------- a1b fp16 (+ folded deg atomic on thread k==65) ----------------
__global__ __launch_bounds__(128) void k_a1(const float* __restrict__ ea,
                                            const float* __restrict__ en1w, const float* __restrict__ en1b,
                                            u16* __restrict__ a1b,
                                            const int* __restrict__ ei, float* __restrict__ deg){
  int e = blockIdx.x, k = threadIdx.x;
  if(k >= A1S) return;
  float v = 0.f;
  if(k < 64){
    float acc = en1b[k];
    #pragma unroll
    for(int c=0;c<4;c++) acc += ea[e*4+c] * en1w[k*4+c];
    v = lrelu(acc);
  } else if(k == 64) v = 1.0f;
  a1b[e*A1S + k] = f2h(v);
  if(k == 65) atomicAdd(&deg[ei[N_EDGES + e]], 1.0f);
}

// ---------------- fused weight-pack kernel (W2b + NodeW + Heads), fp16 ----------------
__global__ __launch_bounds__(256) void k_packAll(const float* __restrict__ en2w, const float* __restrict__ en2b,
                                                 u16* __restrict__ B2b,
                                                 const float* __restrict__ rootw, const float* __restrict__ wih,
                                                 const float* __restrict__ whh, u16* __restrict__ gBn,
                                                 const float* __restrict__ s1w, const float* __restrict__ s2w,
                                                 const float* __restrict__ j1w,
                                                 float4* __restrict__ s1P, float4* __restrict__ s2P,
                                                 float4* __restrict__ j1P){
  int idx = blockIdx.x*256 + threadIdx.x;
  if(idx < PACK_W2B_N){
    int jj  = idx & 7;
    int l   = (idx >> 3) & 63;
    int nt  = (idx >> 9) & 3;
    int c   = idx >> 11;
    int q = l >> 4, m16 = l & 15;
    int kidx = c*32 + q*8 + jj;
    int k = kidx >> 6, j = kidx & 63;
    int o = nt*16 + m16;
    float v = (k < 64) ? en2w[((size_t)(j*64 + o))*64 + k] : en2b[j*64 + o];
    B2b[idx] = f2h(v);
    return;
  }
  idx -= PACK_W2B_N;
  if(idx < PACK_NW_N){
    int jj = idx & 7, l = (idx>>3) & 63, ch = (idx>>9) & 3, t = idx >> 11;
    int m16 = l & 15, q = l >> 4;
    int j = ((ch & 1) ? 32 : 0) + q*8 + jj;
    float v;
    if(t < 4){        int o = t*16 + m16;        v = rootw[j*64 + o]; }
    else if(t < 16){  int g = (t-4)*16 + m16;    v = wih[(size_t)g*64 + j]; }
    else {            int g = (t-16)*16 + m16;   v = whh[(size_t)g*64 + j]; }
    u16 hb = f2h(v);
    gBn[idx] = (ch >> 1) ? f2h(v - h2f(hb)) : hb;
    return;
  }
  idx -= PACK_NW_N;
  if(idx < PACK_HD_N){
    if(idx < 1024){
      int o = idx & 63, j4 = idx >> 6;
      const float* r = s1w + o*64 + 4*j4;
      s1P[idx] = (float4){r[0], r[1], r[2], r[3]};
      const float* r2 = j1w + o*64 + 4*j4;
      j1P[idx] = (float4){r2[0], r2[1], r2[2], r2[3]};
    }
    {
      int j4 = idx / 112, t = idx % 112;
      float4 v = {0.f,0.f,0.f,0.f};
      if(t < 105){
        const float* r = s2w + t*64 + 4*j4;
        v = (float4){r[0], r[1], r[2], r[3]};
      }
      s2P[idx] = v;
    }
  }
}

// ---------------- edge-GEMM v16 (unchanged from R13) ----------------
__global__ __launch_bounds__(512, 2) void k_egemm(const u16* __restrict__ outB,
                                               const u16* __restrict__ a1b,
                                               const u16* __restrict__ B2b,
                                               const int* __restrict__ ei,
                                               float* __restrict__ agg){
  int tid = threadIdx.x;
  int l = tid & 63, w = tid >> 6;          // w in 0..7
  int m16 = l & 15, q = l >> 4;
  int eb = blockIdx.x * EBLK;

  __shared__ __align__(16) u16 a1l[EBLK*A1LS];       // 8448 B
  __shared__ __align__(16) float red[4][EBLK*RS];    // 67584 B (aliased as o2l in prologue)
  uint4* o2l = (uint4*)&red[0][0];                   // [EBLK][O2W], 10240 B

  // cooperative outB gather: exactly one 16B request per (edge, part)
  for(int i = tid; i < EBLK*8; i += 512){
    int el = i >> 3, part = i & 7;
    int e = eb + el;
    int node = (e < N_EDGES) ? ei[e] : 0;
    o2l[el*O2W + part] = *(const uint4*)(outB + (size_t)node*64 + part*8);
  }
  // stage a1 (64 edges x 33 dwords)
  for(int idx = tid; idx < EBLK*33; idx += 512){
    int r = idx / 33, c = idx - r*33;
    int e = eb + r;
    u32 v = (e < N_EDGES) ? ((const u32*)(a1b + (size_t)e*A1S))[c] : 0u;
    ((u32*)a1l)[r*33 + c] = v;
  }
  __syncthreads();

  // per-thread A-operand hoist from LDS
  uint4 oE[4], oO[4];
  #pragma unroll
  for(int t=0;t<4;t++){
    int el = t*16 + m16;
    oE[t] = o2l[el*O2W + q];
    oO[t] = o2l[el*O2W + 4 + q];
  }
  __syncthreads();   // o2l dead from here; red may now be written

  facc4 acc[4][4];
  #pragma unroll
  for(int t=0;t<4;t++)
    #pragma unroll
    for(int nt=0;nt<4;nt++) acc[t][nt] = (facc4){0.f,0.f,0.f,0.f};

  int ks = (w*65) >> 3, ke = ((w+1)*65) >> 3;   // 8,8,8,8,8,8,8,9
  const frag8* __restrict__ Bg = (const frag8*)B2b;

  frag8 bA[4], bB[4];
  #pragma unroll
  for(int nt=0;nt<4;nt++) bA[nt] = Bg[(size_t)(2*ks)*256 + nt*64 + l];

  for(int k = ks; k < ke; ++k){
    #pragma unroll
    for(int nt=0;nt<4;nt++) bB[nt] = Bg[(size_t)(2*k+1)*256 + nt*64 + l];

    u32 av[4];
    #pragma unroll
    for(int t=0;t<4;t++){
      u32 a = a1l[(t*16 + m16)*A1LS + k];
      av[t] = a | (a << 16);
    }

    #pragma unroll
    for(int t=0;t<4;t++){
      frag8 a = pack4h(oE[t], av[t]);
      #pragma unroll
      for(int nt=0;nt<4;nt++)
        acc[t][nt] = __builtin_amdgcn_mfma_f32_16x16x32_f16(a, bA[nt], acc[t][nt], 0,0,0);
    }

    int kn = (k+1 < ke) ? (k+1) : k;
    #pragma unroll
    for(int nt=0;nt<4;nt++) bA[nt] = Bg[(size_t)(2*kn)*256 + nt*64 + l];

    #pragma unroll
    for(int t=0;t<4;t++){
      frag8 a = pack4h(oO[t], av[t]);
      #pragma unroll
      for(int nt=0;nt<4;nt++)
        acc[t][nt] = __builtin_amdgcn_mfma_f32_16x16x32_f16(a, bB[nt], acc[t][nt], 0,0,0);
    }
  }

  // two-phase exclusive-slab reduce (no LDS atomics)
  if(w < 4){
    #pragma unroll
    for(int t=0;t<4;t++)
      #pragma unroll
      for(int nt=0;nt<4;nt++)
        #pragma unroll
        for(int r=0;r<4;r++){
          int el = t*16 + q*4 + r;
          red[w][el*RS + nt*16 + m16] = acc[t][nt][r];
        }
  }
  __syncthreads();
  if(w >= 4){
    #pragma unroll
    for(int t=0;t<4;t++)
      #pragma unroll
      for(int nt=0;nt<4;nt++)
        #pragma unroll
        for(int r=0;r<4;r++){
          int el = t*16 + q*4 + r;
          red[w-4][el*RS + nt*16 + m16] += acc[t][nt][r];
        }
  }
  __syncthreads();

  // one global atomic per (edge, o) — single block touches each (edge,o)
  for(int i = tid; i < EBLK*64; i += 512){
    int el = i >> 6, o = i & 63;
    int e = eb + el;
    if(e < N_EDGES){
      float s = red[0][el*RS + o] + red[1][el*RS + o]
              + red[2][el*RS + o] + red[3][el*RS + o];
      atomicAdd(&agg[(size_t)ei[N_EDGES + e]*64 + o], s);
    }
  }
}

// ---------------- node update v12: PERSISTENT, LDS-resident weights ----------------
// k_node (~18.5us) re-streams the full 114KB gBn from L2 in EVERY one of 938 blocks
// (107MB/dispatch). v12: grid 256 (1 block/CU, LDS-capped), gBn loaded to LDS ONCE
// (27MB total), stride over 3-4 groups. B-frag reads = contiguous ds_read_b128.
// R14 was an infra failure (container acquisition), not a kernel signal; resubmitting.
__global__ __launch_bounds__(256, 1) void k_node(float* __restrict__ agg, const float* __restrict__ deg,
                                              float* __restrict__ outF, u16* __restrict__ outB,
                                              const u16* __restrict__ gBn, const float* __restrict__ convb,
                                              const float* __restrict__ bih, const float* __restrict__ bhh){
  int tid = threadIdx.x;
  int l = tid & 63, w = tid >> 6;
  int m16 = l & 15, q = l >> 4;

  __shared__ __align__(16) u16 gBnL[NWTILES*4*512];   // 114688 B
  __shared__ __align__(16) u16 hhi[16][HS], hlo[16][HS];
  __shared__ __align__(16) u16 mhi[16][HS], mlo[16][HS];

  // load all node-GEMM weights to LDS once (7168 uint4)
  for(int i = tid; i < NWTILES*4*512/8; i += 256)
    ((uint4*)gBnL)[i] = ((const uint4*)gBn)[i];

  int o = w*16 + m16;
  float cb = convb[o];
  float bi0 = bih[o], bi1 = bih[64+o], bi2 = bih[128+o];
  float bh0 = bhh[o], bh1 = bhh[64+o], bh2 = bhh[128+o];

#define GEMM6(ACC, A0, A1, L0, L1, T)                                      \
  {                                                                        \
    const u16* bp = gBnL + (size_t)(T)*2048 + l*8;                         \
    frag8 b0 = *(const frag8*)(bp);                                        \
    frag8 b1 = *(const frag8*)(bp + 512);                                  \
    frag8 b2 = *(const frag8*)(bp + 1024);                                 \
    frag8 b3 = *(const frag8*)(bp + 1536);                                 \
    ACC = __builtin_amdgcn_mfma_f32_16x16x32_f16(A0, b0, ACC, 0,0,0);      \
    ACC = __builtin_amdgcn_mfma_f32_16x16x32_f16(A1, b1, ACC, 0,0,0);      \
    ACC = __builtin_amdgcn_mfma_f32_16x16x32_f16(L0, b0, ACC, 0,0,0);      \
    ACC = __builtin_amdgcn_mfma_f32_16x16x32_f16(L1, b1, ACC, 0,0,0);      \
    ACC = __builtin_amdgcn_mfma_f32_16x16x32_f16(A0, b2, ACC, 0,0,0);      \
    ACC = __builtin_amdgcn_mfma_f32_16x16x32_f16(A1, b3, ACC, 0,0,0);      \
  }

  for(int ng = blockIdx.x; ng < NGROUPS; ng += NODEGRID){
    int nb = ng * 16;
    __syncthreads();   // protects staging reuse across iterations (and gBnL load on iter 0)

    {
      float4 v = ((const float4*)(outF + (size_t)nb*64))[tid];
      int base = tid*4;
      int node = base >> 6, oo = base & 63;
      float vv[4] = {v.x, v.y, v.z, v.w};
      #pragma unroll
      for(int t=0;t<4;t++){
        u16 hb = f2h(vv[t]);
        hhi[node][oo+t] = hb;
        hlo[node][oo+t] = f2h(vv[t] - h2f(hb));
      }
    }
    __syncthreads();

    frag8 hA0 = *(const frag8*)&hhi[m16][q*8];
    frag8 hA1 = *(const frag8*)&hhi[m16][32 + q*8];
    frag8 hL0 = *(const frag8*)&hlo[m16][q*8];
    frag8 hL1 = *(const frag8*)&hlo[m16][32 + q*8];

    facc4 dR  = (facc4){0.f,0.f,0.f,0.f};
    facc4 ghA = (facc4){0.f,0.f,0.f,0.f};
    facc4 ghB = (facc4){0.f,0.f,0.f,0.f};
    facc4 ghC = (facc4){0.f,0.f,0.f,0.f};
    GEMM6(dR,  hA0, hA1, hL0, hL1, w);
    GEMM6(ghA, hA0, hA1, hL0, hL1, 16 + w);
    GEMM6(ghB, hA0, hA1, hL0, hL1, 20 + w);
    GEMM6(ghC, hA0, hA1, hL0, hL1, 24 + w);

    #pragma unroll
    for(int r=0;r<4;r++){
      int node = q*4 + r;
      int n = nb + node;
      float a = agg[(size_t)n*64 + o] / fmaxf(deg[n], 1.0f) + dR[r] + cb;
      agg[(size_t)n*64 + o] = 0.f;
      float mv = lrelu(a);
      u16 mb = f2h(mv);
      mhi[node][o] = mb;
      mlo[node][o] = f2h(mv - h2f(mb));
    }
    __syncthreads();

    frag8 mA0 = *(const frag8*)&mhi[m16][q*8];
    frag8 mA1 = *(const frag8*)&mhi[m16][32 + q*8];
    frag8 mL0 = *(const frag8*)&mlo[m16][q*8];
    frag8 mL1 = *(const frag8*)&mlo[m16][32 + q*8];

    facc4 giA = (facc4){0.f,0.f,0.f,0.f};
    facc4 giB = (facc4){0.f,0.f,0.f,0.f};
    facc4 giC = (facc4){0.f,0.f,0.f,0.f};
    GEMM6(giA, mA0, mA1, mL0, mL1, 4 + w);
    GEMM6(giB, mA0, mA1, mL0, mL1, 8 + w);
    GEMM6(giC, mA0, mA1, mL0, mL1, 12 + w);

    #pragma unroll
    for(int r=0;r<4;r++){
      int node = q*4 + r;
      int n = nb + node;
      float ir = giA[r]+bi0, iz = giB[r]+bi1, inn = giC[r]+bi2;
      float hr = ghA[r]+bh0, hz = ghB[r]+bh1, hn = ghC[r]+bh2;
      float rr  = sigmoidf(ir + hr);
      float z   = sigmoidf(iz + hz);
      float ngv = tanhf(inn + rr*hn);
      float hold = h2f(hhi[node][o]) + h2f(hlo[node][o]);
      float hnew = (1.f - z)*ngv + z*hold;
      if(n < N_NODES){
        outF[(size_t)n*64 + o] = hnew;
        outB[(size_t)n*64 + o] = f2h(hnew);
      }
    }
  }
#undef GEMM6
}

// ---------------- stem head ----------------
__global__ __launch_bounds__(512) void k_stem(const float* __restrict__ outF, const int* __restrict__ sidx,
                                              const float4* __restrict__ s1P, const float* __restrict__ s1b,
                                              const float4* __restrict__ s2P, const float* __restrict__ s2b,
                                              void* __restrict__ dout, const int* __restrict__ flag){
  int grp = threadIdx.x >> 7, t = threadIdx.x & 127;
  int s = blockIdx.x*4 + grp;
  int isf = *flag;
  __shared__ __align__(16) float xs[4][64], hid[4][64];
  int a = sidx[s];
  if(t < 64) xs[grp][t] = outF[(size_t)a*64 + t];
  __syncthreads();
  if(t < 64){
    float acc = s1b[t];
    const float4* xp = (const float4*)xs[grp];
    #pragma unroll 8
    for(int j4=0;j4<16;j4++){
      float4 w = s1P[j4*64+t];
      float4 x = xp[j4];
      acc += w.x*x.x + w.y*x.y + w.z*x.z + w.w*x.w;
    }
    hid[grp][t] = lrelu(acc);
  }
  __syncthreads();
  if(t < 105){
    float acc = s2b[t];
    const float4* hp = (const float4*)hid[grp];
    #pragma unroll 8
    for(int j4=0;j4<16;j4++){
      float4 w = s2P[j4*112+t];
      float4 h = hp[j4];
      acc += w.x*h.x + w.y*h.y + w.z*h.z + w.w*h.w;
    }
    store_out(dout, isf, OUT_STEM + s*105 + t, acc);
  }
}

// ---------------- jbond head ----------------
__global__ __launch_bounds__(512) void k_jbond(const float* __restrict__ outF, const int* __restrict__ jidx,
                                               const float4* __restrict__ j1P, const float* __restrict__ j1b,
                                               const float* __restrict__ j2w, const float* __restrict__ j2b,
                                               void* __restrict__ dout, const int* __restrict__ flag){
  int grp = threadIdx.x >> 7, t = threadIdx.x & 127;
  int jb = blockIdx.x*4 + grp;
  int isf = *flag;
  __shared__ __align__(16) float xs[4][2][64], hid[4][2][64];
  int at = t >> 6, k = t & 63;
  int a = jidx[jb*2 + at];
  xs[grp][at][k] = outF[(size_t)a*64 + k];
  __syncthreads();
  {
    float acc = j1b[k];
    const float4* xp = (const float4*)xs[grp][at];
    #pragma unroll 8
    for(int j4=0;j4<16;j4++){
      float4 w = j1P[j4*64+k];
      float4 x = xp[j4];
      acc += w.x*x.x + w.y*x.y + w.z*x.z + w.w*x.w;
    }
    hid[grp][at][k] = lrelu(acc);
  }
  __syncthreads();
  if(t < 64){
    float p = (hid[grp][0][t] + hid[grp][1][t]) * j2w[t];
    #pragma unroll
    for(int s=32;s;s>>=1) p += __shfl_xor(p, s, 64);
    if(t==0) store_out(dout, isf, OUT_JB + jb, 0.5f*p + j2b[0]);
  }
}

// ---------------- Set2Set + final linear ----------------
__global__ __launch_bounds__(64) void k_s2s(const float* __restrict__ outF, const int* __restrict__ batch,
                                            const float* __restrict__ bih, const float* __restrict__ bhh,
                                            const float* __restrict__ loutw, const float* __restrict__ loutb,
                                            void* __restrict__ dout, const int* __restrict__ flag){
  int b = blockIdx.x, t = threadIdx.x;
  int isf = *flag;
  float i_ = bih[t]     + bhh[t];
  float g_ = bih[128+t] + bhh[128+t];
  float o_ = bih[192+t] + bhh[192+t];
  float c  = sigmoidf(i_)*tanhf(g_);
  float q  = sigmoidf(o_)*tanhf(c);

  int lo = lower_bound_i(batch, N_NODES, b);
  int hi = lower_bound_i(batch, N_NODES, b+1);

  float emax = -3.4e38f;
  for(int n=lo;n<hi;n++){
    float p = outF[n*64+t]*q;
    #pragma unroll
    for(int s=32;s;s>>=1) p += __shfl_xor(p, s, 64);
    emax = fmaxf(emax, p);
  }
  float Z = 0.f, racc = 0.f;
  for(int n=lo;n<hi;n++){
    float v = outF[n*64+t];
    float p = v*q;
    #pragma unroll
    for(int s=32;s;s>>=1) p += __shfl_xor(p, s, 64);
    float w = expf(p - emax);
    Z += w; racc += w*v;
  }
  float rp = (hi>lo) ? racc/Z : 0.f;

  #pragma unroll
  for(int j=0;j<2;j++){
    float p = q*loutw[j*128+t] + rp*loutw[j*128+64+t];
    #pragma unroll
    for(int s=32;s;s>>=1) p += __shfl_xor(p, s, 64);
    if(t==0) store_out(dout, isf, OUT_FINAL + b*2 + j, p + loutb[j]);
  }
}

extern "C" void kernel_launch(void* const* d_in, const int* in_sizes, int n_in,
                              void* d_out, int out_size, void* d_ws, size_t ws_size,
                              hipStream_t stream) {
  const int* edge_index  = (const int*)d_in[28];
  const int* stem_atmidx = (const int*)d_in[29];
  const int* jbond_atmidx= (const int*)d_in[30];
  const int* batch       = (const int*)d_in[31];

  char* ws = (char*)d_ws;
  size_t off = 0;
  auto alloc = [&](size_t bytes)->void*{ void* p = ws + off; off = (off + bytes + 255) & ~(size_t)255; return p; };

  int*   flag = (int*)  alloc(4);
  float* outF = (float*)alloc((size_t)PADN*64*4);
  u16*   outB = (u16*)  alloc((size_t)PADN*64*2);
  float* agg  = (float*)alloc((size_t)PADN*64*4);
  u16*   a1b  = (u16*)  alloc((size_t)N_EDGES*A1S*2);
  u16*   B2b  = (u16*)  alloc((size_t)KCH*2048*2 + 2048*2);   // +1 chunk slack for prefetch tail
  u16*   gBn  = (u16*)  alloc((size_t)NWTILES*4*512*2);       // node-GEMM weights (112 KB)
  float* deg  = (float*)alloc((size_t)PADN*4);
  float4* s1P   = (float4*)alloc(1024*16);
  float4* s2P   = (float4*)alloc(1792*16);
  float4* j1P   = (float4*)alloc(1024*16);

  static const int cvt_idx[N_CVT] = {0,1,2,3,4,5,6,7,8,9,10,11,12,13,14,15,16,17,18,19,20,21,24,25,26,27};
  CvtArgs A;
  float* cF[N_CVT];
  for(int i=0;i<N_CVT;i++){
    int src = cvt_idx[i];
    int n = in_sizes[src];
    cF[i] = (float*)alloc((size_t)n*4);
    A.src[i] = d_in[src];
    A.dst[i] = cF[i];
    A.n[i]   = n;
  }
  (void)ws_size; (void)n_in; (void)out_size;
  float* xF=cF[0];   float* eaF=cF[1];  float* l0w=cF[2];  float* l0b=cF[3];
  float* e1w=cF[4];  float* e1b=cF[5];  float* e2w=cF[6];  float* e2b=cF[7];
  float* rootw=cF[8];float* convb=cF[9];
  float* wih=cF[10]; float* whh=cF[11]; float* bih=cF[12]; float* bhh=cF[13];
  float* s1w=cF[14]; float* s1b=cF[15]; float* s2w=cF[16]; float* s2b=cF[17];
  float* j1w=cF[18]; float* j1b=cF[19]; float* j2w=cF[20]; float* j2b=cF[21];
  float* lbih=cF[22];float* lbhh=cF[23];float* loutw=cF[24];float* loutb=cF[25];

  hipMemsetAsync(flag, 0, 4, stream);

  k_sniff <<<128, 256, 0, stream>>>((const u16*)d_in[0], in_sizes[0], flag, deg, agg, outF, outB);
  k_cvt   <<<512, 256, 0, stream>>>(A, flag);

  k_lin0    <<<N_NODES, 64, 0, stream>>>(xF, l0w, l0b, outF, outB);
  k_a1      <<<N_EDGES, 128, 0, stream>>>(eaF, e1w, e1b, a1b, edge_index, deg);
  k_packAll <<<PACK_TOTAL/256, 256, 0, stream>>>(e2w, e2b, B2b, rootw, wih, whh, gBn,
                                                 s1w, s2w, j1w, s1P, s2P, j1P);

  for(int it=0; it<6; it++){
    k_egemm<<<EGRIDE, 512, 0, stream>>>(outB, a1b, B2b, edge_index, agg);
    k_node <<<NODEGRID, 256, 0, stream>>>(agg, deg, outF, outB, gBn, convb, bih, bhh);
  }

  k_stem <<<N_STEMS/4, 512, 0, stream>>>(outF, stem_atmidx, s1P, s1b, s2P, s2b, d_out, flag);
  k_jbond<<<N_JBONDS/4, 512, 0, stream>>>(outF, jbond_atmidx, j1P, j1b, j2w, j2b, d_out, flag);
  k_s2s  <<<NUM_GRAPHS, 64, 0, stream>>>(outF, batch, lbih, lbhh, loutw, loutb, d_out, flag);
}

// Round 17
// 463.344 us; speedup vs baseline: 1.0532x; 1.0532x over previous
//
#include <hip/hip_runtime.h>

typedef unsigned short u16;
typedef unsigned int   u32;
typedef long long      i64;
typedef unsigned long long u64;

#define N_NODES    15000
#define PADN       15008
#define N_EDGES    30000
#define NUM_GRAPHS 600
#define N_STEMS    6000
#define N_JBONDS   3000

#define OUT_FINAL  0
#define OUT_STEM   1200
#define OUT_JB     631200

#define A1S 68                // a1b (global) row stride u16
#define N_CVT 26

// fixed-point agg scale (determinism: int64 atomics are exact & order-free)
#define AGG_SCALE   16777216.0f          // 2^24
#define AGG_INV     5.9604644775390625e-8f

// ---- edge-GEMM geometry (v16: EBLK=64, LDS-dedup gather) ----
#define EBLK 64               // edges per block (4 MFMA tiles)
#define EGRIDE 469            // ceil(30000/64)
#define KCH 130               // K chunks of 32 (K = 65*64 = 4160)
#define A1LS 66               // a1l row stride u16
#define RS   66               // red row stride f32
#define O2W 10                // o2l row stride in uint4

// ---- k_node (MFMA, per-group) ----
#define NGROUPS (PADN/16)     // 938 groups of 16 nodes
#define NWTILES 28            // root 0-3, wih 4-15, whh 16-27
#define HS 72                 // LDS staging row stride u16

// ---- fused pack kernel segments ----
#define PACK_W2B_N (KCH*2048)        // 266240
#define PACK_NW_N  (NWTILES*4*512)   // 57344
#define PACK_HD_N  1792
#define PACK_TOTAL (PACK_W2B_N + PACK_NW_N + PACK_HD_N)   // 325376 = 1271*256

typedef short frag8 __attribute__((ext_vector_type(8)));   // 8 f16 (4 VGPRs)
typedef float facc4 __attribute__((ext_vector_type(4)));   // 4 f32 acc
typedef _Float16 h16x2 __attribute__((ext_vector_type(2)));

__device__ __forceinline__ float u2f(u16 v){ union{u32 i; float f;} c; c.i=((u32)v)<<16; return c.f; }
__device__ __forceinline__ u16  f2b(float f){ union{float f; u32 u;} c; c.f=f; u32 u=c.u;
                                              return (u16)((u + 0x7fffu + ((u>>16)&1u))>>16); }
__device__ __forceinline__ u16  f2h(float f){ union{_Float16 h; u16 u;} c; c.h = (_Float16)f; return c.u; }
__device__ __forceinline__ float h2f(u16 v){ union{u16 u; _Float16 h;} c; c.u = v; return (float)c.h; }
__device__ __forceinline__ float lrelu(float x){ return x>0.f ? x : 0.01f*x; }
__device__ __forceinline__ float sigmoidf(float x){ return 1.f/(1.f+expf(-x)); }

__device__ __forceinline__ int lower_bound_i(const int* __restrict__ a, int n, int v){
  int lo=0, hi=n;
  while(lo<hi){ int m=(lo+hi)>>1; if(a[m]<v) lo=m+1; else hi=m; }
  return lo;
}

__device__ __forceinline__ void store_out(void* dout, int isf, int idx, float v){
  if(isf) ((float*)dout)[idx] = v;
  else    ((u16*)dout)[idx]   = f2b(v);
}

// fp16 A-fragment: 4x v_pk_mul_f16
__device__ __forceinline__ frag8 pack4h(uint4 v, u32 av2){
  union { u32 d[4]; frag8 f; } au;
  h16x2 a; { union{u32 u; h16x2 h;} c; c.u = av2; a = c.h; }
  { union{u32 u; h16x2 h;} c; c.u = v.x; c.h = a * c.h; au.d[0] = c.u; }
  { union{u32 u; h16x2 h;} c; c.u = v.y; c.h = a * c.h; au.d[1] = c.u; }
  { union{u32 u; h16x2 h;} c; c.u = v.z; c.h = a * c.h; au.d[2] = c.u; }
  { union{u32 u; h16x2 h;} c; c.u = v.w; c.h = a * c.h; au.d[3] = c.u; }
  return au.f;
}

// ---------------- dtype sniff + workspace zero-init ----------------
__global__ __launch_bounds__(256) void k_sniff(const u16* __restrict__ x, int n, int* __restrict__ flag,
                                               float* __restrict__ deg, i64* __restrict__ agg,
                                               float* __restrict__ outF, u16* __restrict__ outB){
  int tid = blockIdx.x*256 + threadIdx.x;
  int stride = gridDim.x*256;
  int local = 0;
  for(int i = tid; i < n; i += stride){
    u16 v = x[i];
    if(((v>>7)&0xFFu) == 0xFFu) local = 1;
  }
  if(local) atomicOr(flag, 1);
  float4 z = (float4){0.f,0.f,0.f,0.f};
  for(int i = tid; i < PADN; i += stride) deg[i] = 0.f;
  for(int i = tid; i < PADN*32; i += stride) ((float4*)agg)[i] = z;   // PADN*64 i64 = PADN*32 float4
  for(int i = tid; i < (PADN-N_NODES)*64/4; i += stride) ((float4*)(outF + (size_t)N_NODES*64))[i] = z;
  for(int i = tid; i < (PADN-N_NODES)*64/8; i += stride) ((float4*)(outB + (size_t)N_NODES*64))[i] = z;
}

// ---------------- convert float inputs to f32 ----------------
struct CvtArgs { const void* src[N_CVT]; float* dst[N_CVT]; int n[N_CVT]; };

__global__ __launch_bounds__(256) void k_cvt(CvtArgs A, const int* __restrict__ flag){
  int isf = *flag;
  int tid = blockIdx.x*256 + threadIdx.x;
  int stride = gridDim.x*256;
  for(int b=0; b<N_CVT; b++){
    int n = A.n[b];
    const float* sf = (const float*)A.src[b];
    const u16*   sb = (const u16*)A.src[b];
    float* d = A.dst[b];
    for(int i=tid; i<n; i+=stride) d[i] = isf ? sf[i] : u2f(sb[i]);
  }
}

// ---------------- lin0 (writes f32 out + fp16 mirror) ----------------
__global__ __launch_bounds__(64) void k_lin0(const float* __restrict__ x, const float* __restrict__ w,
                                             const float* __restrict__ b,
                                             float* __restrict__ outF, u16* __restrict__ outB){
  int n = blockIdx.x, o = threadIdx.x;
  __shared__ float xs[14];
  if(o<14) xs[o] = x[n*14+o];
  __syncthreads();
  float acc = b[o];
  #pragma unroll
  for(int i=0;i<14;i++) acc += xs[i]*w[o*14+i];
  float v = lrelu(acc);
  outF[n*64+o] = v;
  outB[n*64+o] = f2h(v);
}

// ---------------- a1b fp16 (+ folded deg atomic on thread k==65) ----------------
__global__ __launch_bounds__(128) void k_a1(const float* __restrict__ ea,
                                            const float* __restrict__ en1w, const float* __restrict__ en1b,
                                            u16* __restrict__ a1b,
                                            const int* __restrict__ ei, float* __restrict__ deg){
  int e = blockIdx.x, k = threadIdx.x;
  if(k >= A1S) return;
  float v = 0.f;
  if(k < 64){
    float acc = en1b[k];
    #pragma unroll
    for(int c=0;c<4;c++) acc += ea[e*4+c] * en1w[k*4+c];
    v = lrelu(acc);
  } else if(k == 64) v = 1.0f;
  a1b[e*A1S + k] = f2h(v);
  if(k == 65) atomicAdd(&deg[ei[N_EDGES + e]], 1.0f);
}

// ---------------- fused weight-pack kernel (W2b + NodeW + Heads), fp16 ----------------
__global__ __launch_bounds__(256) void k_packAll(const float* __restrict__ en2w, const float* __restrict__ en2b,
                                                 u16* __restrict__ B2b,
                                                 const float* __restrict__ rootw, const float* __restrict__ wih,
                                                 const float* __restrict__ whh, u16* __restrict__ gBn,
                                                 const float* __restrict__ s1w, const float* __restrict__ s2w,
                                                 const float* __restrict__ j1w,
                                                 float4* __restrict__ s1P, float4* __restrict__ s2P,
                                                 float4* __restrict__ j1P){
  int idx = blockIdx.x*256 + threadIdx.x;
  if(idx < PACK_W2B_N){
    int jj  = idx & 7;
    int l   = (idx >> 3) & 63;
    int nt  = (idx >> 9) & 3;
    int c   = idx >> 11;
    int q = l >> 4, m16 = l & 15;
    int kidx = c*32 + q*8 + jj;
    int k = kidx >> 6, j = kidx & 63;
    int o = nt*16 + m16;
    float v = (k < 64) ? en2w[((size_t)(j*64 + o))*64 + k] : en2b[j*64 + o];
    B2b[idx] = f2h(v);
    return;
  }
  idx -= PACK_W2B_N;
  if(idx < PACK_NW_N){
    int jj = idx & 7, l = (idx>>3) & 63, ch = (idx>>9) & 3, t = idx >> 11;
    int m16 = l & 15, q = l >> 4;
    int j = ((ch & 1) ? 32 : 0) + q*8 + jj;
    float v;
    if(t < 4){        int o = t*16 + m16;        v = rootw[j*64 + o]; }
    else if(t < 16){  int g = (t-4)*16 + m16;    v = wih[(size_t)g*64 + j]; }
    else {            int g = (t-16)*16 + m16;   v = whh[(size_t)g*64 + j]; }
    u16 hb = f2h(v);
    gBn[idx] = (ch >> 1) ? f2h(v - h2f(hb)) : hb;
    return;
  }
  idx -= PACK_NW_N;
  if(idx < PACK_HD_N){
    if(idx < 1024){
      int o = idx & 63, j4 = idx >> 6;
      const float* r = s1w + o*64 + 4*j4;
      s1P[idx] = (float4){r[0], r[1], r[2], r[3]};
      const float* r2 = j1w + o*64 + 4*j4;
      j1P[idx] = (float4){r2[0], r2[1], r2[2], r2[3]};
    }
    {
      int j4 = idx / 112, t = idx % 112;
      float4 v = {0.f,0.f,0.f,0.f};
      if(t < 105){
        const float* r = s2w + t*64 + 4*j4;
        v = (float4){r[0], r[1], r[2], r[3]};
      }
      s2P[idx] = v;
    }
  }
}

// ---------------- edge-GEMM v17: v16 + deterministic int64 fixed-point agg ----------------
// R16 post-mortem: identical code to R13 passed once, then failed the post-timing replay
// check (absmax 1.27e-2 vs 6.0e-3) -> latent NONDETERMINISM, not logic. Sole order-dependent
// op: f32 atomicAdd on agg (ordering flips fp16 rounding boundaries in k_node; ulp avalanche
// over 6 iters straddles the threshold). v17: edge contributions scaled by 2^24, rounded
// ONCE (llrintf, deterministic), summed with int64 atomics (exact, order-free). Quantization
// 6e-8/edge << f32 atomic noise. Pipeline now bit-deterministic across replays.
__global__ __launch_bounds__(512, 2) void k_egemm(const u16* __restrict__ outB,
                                               const u16* __restrict__ a1b,
                                               const u16* __restrict__ B2b,
                                               const int* __restrict__ ei,
                                               i64* __restrict__ agg){
  int tid = threadIdx.x;
  int l = tid & 63, w = tid >> 6;          // w in 0..7
  int m16 = l & 15, q = l >> 4;
  int eb = blockIdx.x * EBLK;

  __shared__ __align__(16) u16 a1l[EBLK*A1LS];       // 8448 B
  __shared__ __align__(16) float red[4][EBLK*RS];    // 67584 B (aliased as o2l in prologue)
  uint4* o2l = (uint4*)&red[0][0];                   // [EBLK][O2W], 10240 B

  // cooperative outB gather: exactly one 16B request per (edge, part)
  for(int i = tid; i < EBLK*8; i += 512){
    int el = i >> 3, part = i & 7;
    int e = eb + el;
    int node = (e < N_EDGES) ? ei[e] : 0;
    o2l[el*O2W + part] = *(const uint4*)(outB + (size_t)node*64 + part*8);
  }
  // stage a1 (64 edges x 33 dwords)
  for(int idx = tid; idx < EBLK*33; idx += 512){
    int r = idx / 33, c = idx - r*33;
    int e = eb + r;
    u32 v = (e < N_EDGES) ? ((const u32*)(a1b + (size_t)e*A1S))[c] : 0u;
    ((u32*)a1l)[r*33 + c] = v;
  }
  __syncthreads();

  // per-thread A-operand hoist from LDS
  uint4 oE[4], oO[4];
  #pragma unroll
  for(int t=0;t<4;t++){
    int el = t*16 + m16;
    oE[t] = o2l[el*O2W + q];
    oO[t] = o2l[el*O2W + 4 + q];
  }
  __syncthreads();   // o2l dead from here; red may now be written

  facc4 acc[4][4];
  #pragma unroll
  for(int t=0;t<4;t++)
    #pragma unroll
    for(int nt=0;nt<4;nt++) acc[t][nt] = (facc4){0.f,0.f,0.f,0.f};

  int ks = (w*65) >> 3, ke = ((w+1)*65) >> 3;   // 8,8,8,8,8,8,8,9
  const frag8* __restrict__ Bg = (const frag8*)B2b;

  frag8 bA[4], bB[4];
  #pragma unroll
  for(int nt=0;nt<4;nt++) bA[nt] = Bg[(size_t)(2*ks)*256 + nt*64 + l];

  for(int k = ks; k < ke; ++k){
    #pragma unroll
    for(int nt=0;nt<4;nt++) bB[nt] = Bg[(size_t)(2*k+1)*256 + nt*64 + l];

    u32 av[4];
    #pragma unroll
    for(int t=0;t<4;t++){
      u32 a = a1l[(t*16 + m16)*A1LS + k];
      av[t] = a | (a << 16);
    }

    #pragma unroll
    for(int t=0;t<4;t++){
      frag8 a = pack4h(oE[t], av[t]);
      #pragma unroll
      for(int nt=0;nt<4;nt++)
        acc[t][nt] = __builtin_amdgcn_mfma_f32_16x16x32_f16(a, bA[nt], acc[t][nt], 0,0,0);
    }

    int kn = (k+1 < ke) ? (k+1) : k;
    #pragma unroll
    for(int nt=0;nt<4;nt++) bA[nt] = Bg[(size_t)(2*kn)*256 + nt*64 + l];

    #pragma unroll
    for(int t=0;t<4;t++){
      frag8 a = pack4h(oO[t], av[t]);
      #pragma unroll
      for(int nt=0;nt<4;nt++)
        acc[t][nt] = __builtin_amdgcn_mfma_f32_16x16x32_f16(a, bB[nt], acc[t][nt], 0,0,0);
    }
  }

  // two-phase exclusive-slab reduce (no LDS atomics; fixed order -> deterministic)
  if(w < 4){
    #pragma unroll
    for(int t=0;t<4;t++)
      #pragma unroll
      for(int nt=0;nt<4;nt++)
        #pragma unroll
        for(int r=0;r<4;r++){
          int el = t*16 + q*4 + r;
          red[w][el*RS + nt*16 + m16] = acc[t][nt][r];
        }
  }
  __syncthreads();
  if(w >= 4){
    #pragma unroll
    for(int t=0;t<4;t++)
      #pragma unroll
      for(int nt=0;nt<4;nt++)
        #pragma unroll
        for(int r=0;r<4;r++){
          int el = t*16 + q*4 + r;
          red[w-4][el*RS + nt*16 + m16] += acc[t][nt][r];
        }
  }
  __syncthreads();

  // one int64 fixed-point atomic per (edge, o): exact, order-free
  for(int i = tid; i < EBLK*64; i += 512){
    int el = i >> 6, o = i & 63;
    int e = eb + el;
    if(e < N_EDGES){
      float s = red[0][el*RS + o] + red[1][el*RS + o]
              + red[2][el*RS + o] + red[3][el*RS + o];
      i64 qv = llrintf(s * AGG_SCALE);
      atomicAdd((u64*)&agg[(size_t)ei[N_EDGES + e]*64 + o], (u64)qv);
    }
  }
}

// ---------------- node update: MFMA GRU, per-group (int64 agg read) ----------------
__global__ __launch_bounds__(256) void k_node(i64* __restrict__ agg, const float* __restrict__ deg,
                                              float* __restrict__ outF, u16* __restrict__ outB,
                                              const u16* __restrict__ gBn, const float* __restrict__ convb,
                                              const float* __restrict__ bih, const float* __restrict__ bhh){
  int tid = threadIdx.x;
  int l = tid & 63, w = tid >> 6;
  int m16 = l & 15, q = l >> 4;
  int nb = blockIdx.x * 16;

  __shared__ __align__(16) u16 hhi[16][HS], hlo[16][HS];
  __shared__ __align__(16) u16 mhi[16][HS], mlo[16][HS];

  {
    float4 v = ((const float4*)(outF + (size_t)nb*64))[tid];
    int base = tid*4;
    int node = base >> 6, o = base & 63;
    float vv[4] = {v.x, v.y, v.z, v.w};
    #pragma unroll
    for(int t=0;t<4;t++){
      u16 hb = f2h(vv[t]);
      hhi[node][o+t] = hb;
      hlo[node][o+t] = f2h(vv[t] - h2f(hb));
    }
  }
  __syncthreads();

  const frag8* __restrict__ Bg = (const frag8*)gBn;

#define GEMM6(ACC, A0, A1, L0, L1, T)                                      \
  {                                                                        \
    const frag8* bp = Bg + (size_t)(T)*256 + l;                            \
    frag8 b0 = bp[0], b1 = bp[64], b2 = bp[128], b3 = bp[192];             \
    ACC = __builtin_amdgcn_mfma_f32_16x16x32_f16(A0, b0, ACC, 0,0,0);      \
    ACC = __builtin_amdgcn_mfma_f32_16x16x32_f16(A1, b1, ACC, 0,0,0);      \
    ACC = __builtin_amdgcn_mfma_f32_16x16x32_f16(L0, b0, ACC, 0,0,0);      \
    ACC = __builtin_amdgcn_mfma_f32_16x16x32_f16(L1, b1, ACC, 0,0,0);      \
    ACC = __builtin_amdgcn_mfma_f32_16x16x32_f16(A0, b2, ACC, 0,0,0);      \
    ACC = __builtin_amdgcn_mfma_f32_16x16x32_f16(A1, b3, ACC, 0,0,0);      \
  }

  frag8 hA0 = *(const frag8*)&hhi[m16][q*8];
  frag8 hA1 = *(const frag8*)&hhi[m16][32 + q*8];
  frag8 hL0 = *(const frag8*)&hlo[m16][q*8];
  frag8 hL1 = *(const frag8*)&hlo[m16][32 + q*8];

  facc4 dR  = (facc4){0.f,0.f,0.f,0.f};
  facc4 ghA = (facc4){0.f,0.f,0.f,0.f};
  facc4 ghB = (facc4){0.f,0.f,0.f,0.f};
  facc4 ghC = (facc4){0.f,0.f,0.f,0.f};
  GEMM6(dR,  hA0, hA1, hL0, hL1, w);
  GEMM6(ghA, hA0, hA1, hL0, hL1, 16 + w);
  GEMM6(ghB, hA0, hA1, hL0, hL1, 20 + w);
  GEMM6(ghC, hA0, hA1, hL0, hL1, 24 + w);

  int o = w*16 + m16;
  float cb = convb[o];
  #pragma unroll
  for(int r=0;r<4;r++){
    int node = q*4 + r;
    int n = nb + node;
    i64 vq = agg[(size_t)n*64 + o];
    agg[(size_t)n*64 + o] = 0ll;
    float av = (float)vq * AGG_INV;
    float a = av / fmaxf(deg[n], 1.0f) + dR[r] + cb;
    float mv = lrelu(a);
    u16 mb = f2h(mv);
    mhi[node][o] = mb;
    mlo[node][o] = f2h(mv - h2f(mb));
  }
  __syncthreads();

  frag8 mA0 = *(const frag8*)&mhi[m16][q*8];
  frag8 mA1 = *(const frag8*)&mhi[m16][32 + q*8];
  frag8 mL0 = *(const frag8*)&mlo[m16][q*8];
  frag8 mL1 = *(const frag8*)&mlo[m16][32 + q*8];

  facc4 giA = (facc4){0.f,0.f,0.f,0.f};
  facc4 giB = (facc4){0.f,0.f,0.f,0.f};
  facc4 giC = (facc4){0.f,0.f,0.f,0.f};
  GEMM6(giA, mA0, mA1, mL0, mL1, 4 + w);
  GEMM6(giB, mA0, mA1, mL0, mL1, 8 + w);
  GEMM6(giC, mA0, mA1, mL0, mL1, 12 + w);
#undef GEMM6

  float bi0 = bih[o], bi1 = bih[64+o], bi2 = bih[128+o];
  float bh0 = bhh[o], bh1 = bhh[64+o], bh2 = bhh[128+o];
  #pragma unroll
  for(int r=0;r<4;r++){
    int node = q*4 + r;
    int n = nb + node;
    float ir = giA[r]+bi0, iz = giB[r]+bi1, inn = giC[r]+bi2;
    float hr = ghA[r]+bh0, hz = ghB[r]+bh1, hn = ghC[r]+bh2;
    float rr  = sigmoidf(ir + hr);
    float z   = sigmoidf(iz + hz);
    float ngv = tanhf(inn + rr*hn);
    float hold = h2f(hhi[node][o]) + h2f(hlo[node][o]);
    float hnew = (1.f - z)*ngv + z*hold;
    if(n < N_NODES){
      outF[(size_t)n*64 + o] = hnew;
      outB[(size_t)n*64 + o] = f2h(hnew);
    }
  }
}

// ---------------- stem head ----------------
__global__ __launch_bounds__(512) void k_stem(const float* __restrict__ outF, const int* __restrict__ sidx,
                                              const float4* __restrict__ s1P, const float* __restrict__ s1b,
                                              const float4* __restrict__ s2P, const float* __restrict__ s2b,
                                              void* __restrict__ dout, const int* __restrict__ flag){
  int grp = threadIdx.x >> 7, t = threadIdx.x & 127;
  int s = blockIdx.x*4 + grp;
  int isf = *flag;
  __shared__ __align__(16) float xs[4][64], hid[4][64];
  int a = sidx[s];
  if(t < 64) xs[grp][t] = outF[(size_t)a*64 + t];
  __syncthreads();
  if(t < 64){
    float acc = s1b[t];
    const float4* xp = (const float4*)xs[grp];
    #pragma unroll 8
    for(int j4=0;j4<16;j4++){
      float4 w = s1P[j4*64+t];
      float4 x = xp[j4];
      acc += w.x*x.x + w.y*x.y + w.z*x.z + w.w*x.w;
    }
    hid[grp][t] = lrelu(acc);
  }
  __syncthreads();
  if(t < 105){
    float acc = s2b[t];
    const float4* hp = (const float4*)hid[grp];
    #pragma unroll 8
    for(int j4=0;j4<16;j4++){
      float4 w = s2P[j4*112+t];
      float4 h = hp[j4];
      acc += w.x*h.x + w.y*h.y + w.z*h.z + w.w*h.w;
    }
    store_out(dout, isf, OUT_STEM + s*105 + t, acc);
  }
}

// ---------------- jbond head ----------------
__global__ __launch_bounds__(512) void k_jbond(const float* __restrict__ outF, const int* __restrict__ jidx,
                                               const float4* __restrict__ j1P, const float* __restrict__ j1b,
                                               const float* __restrict__ j2w, const float* __restrict__ j2b,
                                               void* __restrict__ dout, const int* __restrict__ flag){
  int grp = threadIdx.x >> 7, t = threadIdx.x & 127;
  int jb = blockIdx.x*4 + grp;
  int isf = *flag;
  __shared__ __align__(16) float xs[4][2][64], hid[4][2][64];
  int at = t >> 6, k = t & 63;
  int a = jidx[jb*2 + at];
  xs[grp][at][k] = outF[(size_t)a*64 + k];
  __syncthreads();
  {
    float acc = j1b[k];
    const float4* xp = (const float4*)xs[grp][at];
    #pragma unroll 8
    for(int j4=0;j4<16;j4++){
      float4 w = j1P[j4*64+k];
      float4 x = xp[j4];
      acc += w.x*x.x + w.y*x.y + w.z*x.z + w.w*x.w;
    }
    hid[grp][at][k] = lrelu(acc);
  }
  __syncthreads();
  if(t < 64){
    float p = (hid[grp][0][t] + hid[grp][1][t]) * j2w[t];
    #pragma unroll
    for(int s=32;s;s>>=1) p += __shfl_xor(p, s, 64);
    if(t==0) store_out(dout, isf, OUT_JB + jb, 0.5f*p + j2b[0]);
  }
}

// ---------------- Set2Set + final linear ----------------
__global__ __launch_bounds__(64) void k_s2s(const float* __restrict__ outF, const int* __restrict__ batch,
                                            const float* __restrict__ bih, const float* __restrict__ bhh,
                                            const float* __restrict__ loutw, const float* __restrict__ loutb,
                                            void* __restrict__ dout, const int* __restrict__ flag){
  int b = blockIdx.x, t = threadIdx.x;
  int isf = *flag;
  float i_ = bih[t]     + bhh[t];
  float g_ = bih[128+t] + bhh[128+t];
  float o_ = bih[192+t] + bhh[192+t];
  float c  = sigmoidf(i_)*tanhf(g_);
  float q  = sigmoidf(o_)*tanhf(c);

  int lo = lower_bound_i(batch, N_NODES, b);
  int hi = lower_bound_i(batch, N_NODES, b+1);

  float emax = -3.4e38f;
  for(int n=lo;n<hi;n++){
    float p = outF[n*64+t]*q;
    #pragma unroll
    for(int s=32;s;s>>=1) p += __shfl_xor(p, s, 64);
    emax = fmaxf(emax, p);
  }
  float Z = 0.f, racc = 0.f;
  for(int n=lo;n<hi;n++){
    float v = outF[n*64+t];
    float p = v*q;
    #pragma unroll
    for(int s=32;s;s>>=1) p += __shfl_xor(p, s, 64);
    float w = expf(p - emax);
    Z += w; racc += w*v;
  }
  float rp = (hi>lo) ? racc/Z : 0.f;

  #pragma unroll
  for(int j=0;j<2;j++){
    float p = q*loutw[j*128+t] + rp*loutw[j*128+64+t];
    #pragma unroll
    for(int s=32;s;s>>=1) p += __shfl_xor(p, s, 64);
    if(t==0) store_out(dout, isf, OUT_FINAL + b*2 + j, p + loutb[j]);
  }
}

extern "C" void kernel_launch(void* const* d_in, const int* in_sizes, int n_in,
                              void* d_out, int out_size, void* d_ws, size_t ws_size,
                              hipStream_t stream) {
  const int* edge_index  = (const int*)d_in[28];
  const int* stem_atmidx = (const int*)d_in[29];
  const int* jbond_atmidx= (const int*)d_in[30];
  const int* batch       = (const int*)d_in[31];

  char* ws = (char*)d_ws;
  size_t off = 0;
  auto alloc = [&](size_t bytes)->void*{ void* p = ws + off; off = (off + bytes + 255) & ~(size_t)255; return p; };

  int*   flag = (int*)  alloc(4);
  float* outF = (float*)alloc((size_t)PADN*64*4);
  u16*   outB = (u16*)  alloc((size_t)PADN*64*2);
  i64*   agg  = (i64*)  alloc((size_t)PADN*64*8);
  u16*   a1b  = (u16*)  alloc((size_t)N_EDGES*A1S*2);
  u16*   B2b  = (u16*)  alloc((size_t)KCH*2048*2 + 2048*2);   // +1 chunk slack for prefetch tail
  u16*   gBn  = (u16*)  alloc((size_t)NWTILES*4*512*2);       // node-GEMM weights (112 KB)
  float* deg  = (float*)alloc((size_t)PADN*4);
  float4* s1P   = (float4*)alloc(1024*16);
  float4* s2P   = (float4*)alloc(1792*16);
  float4* j1P   = (float4*)alloc(1024*16);

  static const int cvt_idx[N_CVT] = {0,1,2,3,4,5,6,7,8,9,10,11,12,13,14,15,16,17,18,19,20,21,24,25,26,27};
  CvtArgs A;
  float* cF[N_CVT];
  for(int i=0;i<N_CVT;i++){
    int src = cvt_idx[i];
    int n = in_sizes[src];
    cF[i] = (float*)alloc((size_t)n*4);
    A.src[i] = d_in[src];
    A.dst[i] = cF[i];
    A.n[i]   = n;
  }
  (void)ws_size; (void)n_in; (void)out_size;
  float* xF=cF[0];   float* eaF=cF[1];  float* l0w=cF[2];  float* l0b=cF[3];
  float* e1w=cF[4];  float* e1b=cF[5];  float* e2w=cF[6];  float* e2b=cF[7];
  float* rootw=cF[8];float* convb=cF[9];
  float* wih=cF[10]; float* whh=cF[11]; float* bih=cF[12]; float* bhh=cF[13];
  float* s1w=cF[14]; float* s1b=cF[15]; float* s2w=cF[16]; float* s2b=cF[17];
  float* j1w=cF[18]; float* j1b=cF[19]; float* j2w=cF[20]; float* j2b=cF[21];
  float* lbih=cF[22];float* lbhh=cF[23];float* loutw=cF[24];float* loutb=cF[25];

  hipMemsetAsync(flag, 0, 4, stream);

  k_sniff <<<128, 256, 0, stream>>>((const u16*)d_in[0], in_sizes[0], flag, deg, agg, outF, outB);
  k_cvt   <<<512, 256, 0, stream>>>(A, flag);

  k_lin0    <<<N_NODES, 64, 0, stream>>>(xF, l0w, l0b, outF, outB);
  k_a1      <<<N_EDGES, 128, 0, stream>>>(eaF, e1w, e1b, a1b, edge_index, deg);
  k_packAll <<<PACK_TOTAL/256, 256, 0, stream>>>(e2w, e2b, B2b, rootw, wih, whh, gBn,
                                                 s1w, s2w, j1w, s1P, s2P, j1P);

  for(int it=0; it<6; it++){
    k_egemm<<<EGRIDE, 512, 0, stream>>>(outB, a1b, B2b, edge_index, agg);
    k_node <<<NGROUPS, 256, 0, stream>>>(agg, deg, outF, outB, gBn, convb, bih, bhh);
  }

  k_stem <<<N_STEMS/4, 512, 0, stream>>>(outF, stem_atmidx, s1P, s1b, s2P, s2b, d_out, flag);
  k_jbond<<<N_JBONDS/4, 512, 0, stream>>>(outF, jbond_atmidx, j1P, j1b, j2w, j2b, d_out, flag);
  k_s2s  <<<NUM_GRAPHS, 64, 0, stream>>>(outF, batch, lbih, lbhh, loutw, loutb, d_out, flag);
}

// Round 18
// 414.685 us; speedup vs baseline: 1.1768x; 1.1173x over previous
//
#include <hip/hip_runtime.h>

typedef unsigned short u16;
typedef unsigned int   u32;

#define N_NODES    15000
#define PADN       15008
#define N_EDGES    30000
#define NUM_GRAPHS 600
#define N_STEMS    6000
#define N_JBONDS   3000

#define OUT_FINAL  0
#define OUT_STEM   1200
#define OUT_JB     631200

#define A1S 68                // a1b (global) row stride u16
#define N_CVT 26

// fixed-point agg scale (determinism: int atomics exact & order-free).
// i32 @ 2^17: overflow needs |sum| > 16384 (observed O(1-10), margin >1000x);
// quantization 3.8e-6/edge << 2e-3 bf16 output rounding.
#define AGG_SCALE   131072.0f            // 2^17
#define AGG_INV     7.62939453125e-6f    // 2^-17

// ---- edge-GEMM geometry (v16: EBLK=64, LDS-dedup gather) ----
#define EBLK 64               // edges per block (4 MFMA tiles)
#define EGRIDE 469            // ceil(30000/64)
#define KCH 130               // K chunks of 32 (K = 65*64 = 4160)
#define A1LS 66               // a1l row stride u16
#define RS   66               // red row stride f32
#define O2W 10                // o2l row stride in uint4

// ---- k_node (MFMA, per-group) ----
#define NGROUPS (PADN/16)     // 938 groups of 16 nodes
#define NWTILES 28            // root 0-3, wih 4-15, whh 16-27
#define HS 72                 // LDS staging row stride u16

// ---- fused pack kernel segments ----
#define PACK_W2B_N (KCH*2048)        // 266240
#define PACK_NW_N  (NWTILES*4*512)   // 57344
#define PACK_HD_N  1792
#define PACK_TOTAL (PACK_W2B_N + PACK_NW_N + PACK_HD_N)   // 325376 = 1271*256

typedef short frag8 __attribute__((ext_vector_type(8)));   // 8 f16 (4 VGPRs)
typedef float facc4 __attribute__((ext_vector_type(4)));   // 4 f32 acc
typedef _Float16 h16x2 __attribute__((ext_vector_type(2)));

__device__ __forceinline__ float u2f(u16 v){ union{u32 i; float f;} c; c.i=((u32)v)<<16; return c.f; }
__device__ __forceinline__ u16  f2b(float f){ union{float f; u32 u;} c; c.f=f; u32 u=c.u;
                                              return (u16)((u + 0x7fffu + ((u>>16)&1u))>>16); }
__device__ __forceinline__ u16  f2h(float f){ union{_Float16 h; u16 u;} c; c.h = (_Float16)f; return c.u; }
__device__ __forceinline__ float h2f(u16 v){ union{u16 u; _Float16 h;} c; c.u = v; return (float)c.h; }
__device__ __forceinline__ float lrelu(float x){ return x>0.f ? x : 0.01f*x; }
__device__ __forceinline__ float sigmoidf(float x){ return 1.f/(1.f+expf(-x)); }

__device__ __forceinline__ int lower_bound_i(const int* __restrict__ a, int n, int v){
  int lo=0, hi=n;
  while(lo<hi){ int m=(lo+hi)>>1; if(a[m]<v) lo=m+1; else hi=m; }
  return lo;
}

__device__ __forceinline__ void store_out(void* dout, int isf, int idx, float v){
  if(isf) ((float*)dout)[idx] = v;
  else    ((u16*)dout)[idx]   = f2b(v);
}

// fp16 A-fragment: 4x v_pk_mul_f16
__device__ __forceinline__ frag8 pack4h(uint4 v, u32 av2){
  union { u32 d[4]; frag8 f; } au;
  h16x2 a; { union{u32 u; h16x2 h;} c; c.u = av2; a = c.h; }
  { union{u32 u; h16x2 h;} c; c.u = v.x; c.h = a * c.h; au.d[0] = c.u; }
  { union{u32 u; h16x2 h;} c; c.u = v.y; c.h = a * c.h; au.d[1] = c.u; }
  { union{u32 u; h16x2 h;} c; c.u = v.z; c.h = a * c.h; au.d[2] = c.u; }
  { union{u32 u; h16x2 h;} c; c.u = v.w; c.h = a * c.h; au.d[3] = c.u; }
  return au.f;
}

// ---------------- dtype sniff + workspace zero-init ----------------
__global__ __launch_bounds__(256) void k_sniff(const u16* __restrict__ x, int n, int* __restrict__ flag,
                                               float* __restrict__ deg, int* __restrict__ agg,
                                               float* __restrict__ outF, u16* __restrict__ outB){
  int tid = blockIdx.x*256 + threadIdx.x;
  int stride = gridDim.x*256;
  int local = 0;
  for(int i = tid; i < n; i += stride){
    u16 v = x[i];
    if(((v>>7)&0xFFu) == 0xFFu) local = 1;
  }
  if(local) atomicOr(flag, 1);
  float4 z = (float4){0.f,0.f,0.f,0.f};
  for(int i = tid; i < PADN; i += stride) deg[i] = 0.f;
  for(int i = tid; i < PADN*16; i += stride) ((float4*)agg)[i] = z;   // PADN*64 i32
  for(int i = tid; i < (PADN-N_NODES)*64/4; i += stride) ((float4*)(outF + (size_t)N_NODES*64))[i] = z;
  for(int i = tid; i < (PADN-N_NODES)*64/8; i += stride) ((float4*)(outB + (size_t)N_NODES*64))[i] = z;
}

// ---------------- convert float inputs to f32 ----------------
struct CvtArgs { const void* src[N_CVT]; float* dst[N_CVT]; int n[N_CVT]; };

__global__ __launch_bounds__(256) void k_cvt(CvtArgs A, const int* __restrict__ flag){
  int isf = *flag;
  int tid = blockIdx.x*256 + threadIdx.x;
  int stride = gridDim.x*256;
  for(int b=0; b<N_CVT; b++){
    int n = A.n[b];
    const float* sf = (const float*)A.src[b];
    const u16*   sb = (const u16*)A.src[b];
    float* d = A.dst[b];
    for(int i=tid; i<n; i+=stride) d[i] = isf ? sf[i] : u2f(sb[i]);
  }
}

// ---------------- lin0 (writes f32 out + fp16 mirror) ----------------
__global__ __launch_bounds__(64) void k_lin0(const float* __restrict__ x, const float* __restrict__ w,
                                             const float* __restrict__ b,
                                             float* __restrict__ outF, u16* __restrict__ outB){
  int n = blockIdx.x, o = threadIdx.x;
  __shared__ float xs[14];
  if(o<14) xs[o] = x[n*14+o];
  __syncthreads();
  float acc = b[o];
  #pragma unroll
  for(int i=0;i<14;i++) acc += xs[i]*w[o*14+i];
  float v = lrelu(acc);
  outF[n*64+o] = v;
  outB[n*64+o] = f2h(v);
}

// ---------------- a1b fp16 (+ folded deg atomic on thread k==65) ----------------
__global__ __launch_bounds__(128) void k_a1(const float* __restrict__ ea,
                                            const float* __restrict__ en1w, const float* __restrict__ en1b,
                                            u16* __restrict__ a1b,
                                            const int* __restrict__ ei, float* __restrict__ deg){
  int e = blockIdx.x, k = threadIdx.x;
  if(k >= A1S) return;
  float v = 0.f;
  if(k < 64){
    float acc = en1b[k];
    #pragma unroll
    for(int c=0;c<4;c++) acc += ea[e*4+c] * en1w[k*4+c];
    v = lrelu(acc);
  } else if(k == 64) v = 1.0f;
  a1b[e*A1S + k] = f2h(v);
  if(k == 65) atomicAdd(&deg[ei[N_EDGES + e]], 1.0f);
}

// ---------------- fused weight-pack kernel (W2b + NodeW + Heads), fp16 ----------------
__global__ __launch_bounds__(256) void k_packAll(const float* __restrict__ en2w, const float* __restrict__ en2b,
                                                 u16* __restrict__ B2b,
                                                 const float* __restrict__ rootw, const float* __restrict__ wih,
                                                 const float* __restrict__ whh, u16* __restrict__ gBn,
                                                 const float* __restrict__ s1w, const float* __restrict__ s2w,
                                                 const float* __restrict__ j1w,
                                                 float4* __restrict__ s1P, float4* __restrict__ s2P,
                                                 float4* __restrict__ j1P){
  int idx = blockIdx.x*256 + threadIdx.x;
  if(idx < PACK_W2B_N){
    int jj  = idx & 7;
    int l   = (idx >> 3) & 63;
    int nt  = (idx >> 9) & 3;
    int c   = idx >> 11;
    int q = l >> 4, m16 = l & 15;
    int kidx = c*32 + q*8 + jj;
    int k = kidx >> 6, j = kidx & 63;
    int o = nt*16 + m16;
    float v = (k < 64) ? en2w[((size_t)(j*64 + o))*64 + k] : en2b[j*64 + o];
    B2b[idx] = f2h(v);
    return;
  }
  idx -= PACK_W2B_N;
  if(idx < PACK_NW_N){
    int jj = idx & 7, l = (idx>>3) & 63, ch = (idx>>9) & 3, t = idx >> 11;
    int m16 = l & 15, q = l >> 4;
    int j = ((ch & 1) ? 32 : 0) + q*8 + jj;
    float v;
    if(t < 4){        int o = t*16 + m16;        v = rootw[j*64 + o]; }
    else if(t < 16){  int g = (t-4)*16 + m16;    v = wih[(size_t)g*64 + j]; }
    else {            int g = (t-16)*16 + m16;   v = whh[(size_t)g*64 + j]; }
    u16 hb = f2h(v);
    gBn[idx] = (ch >> 1) ? f2h(v - h2f(hb)) : hb;
    return;
  }
  idx -= PACK_NW_N;
  if(idx < PACK_HD_N){
    if(idx < 1024){
      int o = idx & 63, j4 = idx >> 6;
      const float* r = s1w + o*64 + 4*j4;
      s1P[idx] = (float4){r[0], r[1], r[2], r[3]};
      const float* r2 = j1w + o*64 + 4*j4;
      j1P[idx] = (float4){r2[0], r2[1], r2[2], r2[3]};
    }
    {
      int j4 = idx / 112, t = idx % 112;
      float4 v = {0.f,0.f,0.f,0.f};
      if(t < 105){
        const float* r = s2w + t*64 + 4*j4;
        v = (float4){r[0], r[1], r[2], r[3]};
      }
      s2P[idx] = v;
    }
  }
}

// ---------------- edge-GEMM v18: v16 + deterministic i32 fixed-point agg ----------------
// R17 post-mortem: int64 agg fixed determinism (+pass) but cost +31us (2x agg footprint,
// 2x atomic bytes, 2x k_node agg traffic). v18: i32 @ 2^17 — same exact order-free integer
// sum (bit-deterministic), traffic identical to the 432us R13 profile. Overflow margin
// >1000x; quantization 3.8e-6/edge << bf16 output rounding.
__global__ __launch_bounds__(512, 2) void k_egemm(const u16* __restrict__ outB,
                                               const u16* __restrict__ a1b,
                                               const u16* __restrict__ B2b,
                                               const int* __restrict__ ei,
                                               int* __restrict__ agg){
  int tid = threadIdx.x;
  int l = tid & 63, w = tid >> 6;          // w in 0..7
  int m16 = l & 15, q = l >> 4;
  int eb = blockIdx.x * EBLK;

  __shared__ __align__(16) u16 a1l[EBLK*A1LS];       // 8448 B
  __shared__ __align__(16) float red[4][EBLK*RS];    // 67584 B (aliased as o2l in prologue)
  uint4* o2l = (uint4*)&red[0][0];                   // [EBLK][O2W], 10240 B

  // cooperative outB gather: exactly one 16B request per (edge, part)
  for(int i = tid; i < EBLK*8; i += 512){
    int el = i >> 3, part = i & 7;
    int e = eb + el;
    int node = (e < N_EDGES) ? ei[e] : 0;
    o2l[el*O2W + part] = *(const uint4*)(outB + (size_t)node*64 + part*8);
  }
  // stage a1 (64 edges x 33 dwords)
  for(int idx = tid; idx < EBLK*33; idx += 512){
    int r = idx / 33, c = idx - r*33;
    int e = eb + r;
    u32 v = (e < N_EDGES) ? ((const u32*)(a1b + (size_t)e*A1S))[c] : 0u;
    ((u32*)a1l)[r*33 + c] = v;
  }
  __syncthreads();

  // per-thread A-operand hoist from LDS
  uint4 oE[4], oO[4];
  #pragma unroll
  for(int t=0;t<4;t++){
    int el = t*16 + m16;
    oE[t] = o2l[el*O2W + q];
    oO[t] = o2l[el*O2W + 4 + q];
  }
  __syncthreads();   // o2l dead from here; red may now be written

  facc4 acc[4][4];
  #pragma unroll
  for(int t=0;t<4;t++)
    #pragma unroll
    for(int nt=0;nt<4;nt++) acc[t][nt] = (facc4){0.f,0.f,0.f,0.f};

  int ks = (w*65) >> 3, ke = ((w+1)*65) >> 3;   // 8,8,8,8,8,8,8,9
  const frag8* __restrict__ Bg = (const frag8*)B2b;

  frag8 bA[4], bB[4];
  #pragma unroll
  for(int nt=0;nt<4;nt++) bA[nt] = Bg[(size_t)(2*ks)*256 + nt*64 + l];

  for(int k = ks; k < ke; ++k){
    #pragma unroll
    for(int nt=0;nt<4;nt++) bB[nt] = Bg[(size_t)(2*k+1)*256 + nt*64 + l];

    u32 av[4];
    #pragma unroll
    for(int t=0;t<4;t++){
      u32 a = a1l[(t*16 + m16)*A1LS + k];
      av[t] = a | (a << 16);
    }

    #pragma unroll
    for(int t=0;t<4;t++){
      frag8 a = pack4h(oE[t], av[t]);
      #pragma unroll
      for(int nt=0;nt<4;nt++)
        acc[t][nt] = __builtin_amdgcn_mfma_f32_16x16x32_f16(a, bA[nt], acc[t][nt], 0,0,0);
    }

    int kn = (k+1 < ke) ? (k+1) : k;
    #pragma unroll
    for(int nt=0;nt<4;nt++) bA[nt] = Bg[(size_t)(2*kn)*256 + nt*64 + l];

    #pragma unroll
    for(int t=0;t<4;t++){
      frag8 a = pack4h(oO[t], av[t]);
      #pragma unroll
      for(int nt=0;nt<4;nt++)
        acc[t][nt] = __builtin_amdgcn_mfma_f32_16x16x32_f16(a, bB[nt], acc[t][nt], 0,0,0);
    }
  }

  // two-phase exclusive-slab reduce (no LDS atomics; fixed order -> deterministic)
  if(w < 4){
    #pragma unroll
    for(int t=0;t<4;t++)
      #pragma unroll
      for(int nt=0;nt<4;nt++)
        #pragma unroll
        for(int r=0;r<4;r++){
          int el = t*16 + q*4 + r;
          red[w][el*RS + nt*16 + m16] = acc[t][nt][r];
        }
  }
  __syncthreads();
  if(w >= 4){
    #pragma unroll
    for(int t=0;t<4;t++)
      #pragma unroll
      for(int nt=0;nt<4;nt++)
        #pragma unroll
        for(int r=0;r<4;r++){
          int el = t*16 + q*4 + r;
          red[w-4][el*RS + nt*16 + m16] += acc[t][nt][r];
        }
  }
  __syncthreads();

  // one i32 fixed-point atomic per (edge, o): exact, order-free
  for(int i = tid; i < EBLK*64; i += 512){
    int el = i >> 6, o = i & 63;
    int e = eb + el;
    if(e < N_EDGES){
      float s = red[0][el*RS + o] + red[1][el*RS + o]
              + red[2][el*RS + o] + red[3][el*RS + o];
      int qv = (int)lrintf(s * AGG_SCALE);
      atomicAdd(&agg[(size_t)ei[N_EDGES + e]*64 + o], qv);
    }
  }
}

// ---------------- node update: MFMA GRU, per-group (i32 agg read) ----------------
__global__ __launch_bounds__(256) void k_node(int* __restrict__ agg, const float* __restrict__ deg,
                                              float* __restrict__ outF, u16* __restrict__ outB,
                                              const u16* __restrict__ gBn, const float* __restrict__ convb,
                                              const float* __restrict__ bih, const float* __restrict__ bhh){
  int tid = threadIdx.x;
  int l = tid & 63, w = tid >> 6;
  int m16 = l & 15, q = l >> 4;
  int nb = blockIdx.x * 16;

  __shared__ __align__(16) u16 hhi[16][HS], hlo[16][HS];
  __shared__ __align__(16) u16 mhi[16][HS], mlo[16][HS];

  {
    float4 v = ((const float4*)(outF + (size_t)nb*64))[tid];
    int base = tid*4;
    int node = base >> 6, o = base & 63;
    float vv[4] = {v.x, v.y, v.z, v.w};
    #pragma unroll
    for(int t=0;t<4;t++){
      u16 hb = f2h(vv[t]);
      hhi[node][o+t] = hb;
      hlo[node][o+t] = f2h(vv[t] - h2f(hb));
    }
  }
  __syncthreads();

  const frag8* __restrict__ Bg = (const frag8*)gBn;

#define GEMM6(ACC, A0, A1, L0, L1, T)                                      \
  {                                                                        \
    const frag8* bp = Bg + (size_t)(T)*256 + l;                            \
    frag8 b0 = bp[0], b1 = bp[64], b2 = bp[128], b3 = bp[192];             \
    ACC = __builtin_amdgcn_mfma_f32_16x16x32_f16(A0, b0, ACC, 0,0,0);      \
    ACC = __builtin_amdgcn_mfma_f32_16x16x32_f16(A1, b1, ACC, 0,0,0);      \
    ACC = __builtin_amdgcn_mfma_f32_16x16x32_f16(L0, b0, ACC, 0,0,0);      \
    ACC = __builtin_amdgcn_mfma_f32_16x16x32_f16(L1, b1, ACC, 0,0,0);      \
    ACC = __builtin_amdgcn_mfma_f32_16x16x32_f16(A0, b2, ACC, 0,0,0);      \
    ACC = __builtin_amdgcn_mfma_f32_16x16x32_f16(A1, b3, ACC, 0,0,0);      \
  }

  frag8 hA0 = *(const frag8*)&hhi[m16][q*8];
  frag8 hA1 = *(const frag8*)&hhi[m16][32 + q*8];
  frag8 hL0 = *(const frag8*)&hlo[m16][q*8];
  frag8 hL1 = *(const frag8*)&hlo[m16][32 + q*8];

  facc4 dR  = (facc4){0.f,0.f,0.f,0.f};
  facc4 ghA = (facc4){0.f,0.f,0.f,0.f};
  facc4 ghB = (facc4){0.f,0.f,0.f,0.f};
  facc4 ghC = (facc4){0.f,0.f,0.f,0.f};
  GEMM6(dR,  hA0, hA1, hL0, hL1, w);
  GEMM6(ghA, hA0, hA1, hL0, hL1, 16 + w);
  GEMM6(ghB, hA0, hA1, hL0, hL1, 20 + w);
  GEMM6(ghC, hA0, hA1, hL0, hL1, 24 + w);

  int o = w*16 + m16;
  float cb = convb[o];
  #pragma unroll
  for(int r=0;r<4;r++){
    int node = q*4 + r;
    int n = nb + node;
    int vq = agg[(size_t)n*64 + o];
    agg[(size_t)n*64 + o] = 0;
    float av = (float)vq * AGG_INV;
    float a = av / fmaxf(deg[n], 1.0f) + dR[r] + cb;
    float mv = lrelu(a);
    u16 mb = f2h(mv);
    mhi[node][o] = mb;
    mlo[node][o] = f2h(mv - h2f(mb));
  }
  __syncthreads();

  frag8 mA0 = *(const frag8*)&mhi[m16][q*8];
  frag8 mA1 = *(const frag8*)&mhi[m16][32 + q*8];
  frag8 mL0 = *(const frag8*)&mlo[m16][q*8];
  frag8 mL1 = *(const frag8*)&mlo[m16][32 + q*8];

  facc4 giA = (facc4){0.f,0.f,0.f,0.f};
  facc4 giB = (facc4){0.f,0.f,0.f,0.f};
  facc4 giC = (facc4){0.f,0.f,0.f,0.f};
  GEMM6(giA, mA0, mA1, mL0, mL1, 4 + w);
  GEMM6(giB, mA0, mA1, mL0, mL1, 8 + w);
  GEMM6(giC, mA0, mA1, mL0, mL1, 12 + w);
#undef GEMM6

  float bi0 = bih[o], bi1 = bih[64+o], bi2 = bih[128+o];
  float bh0 = bhh[o], bh1 = bhh[64+o], bh2 = bhh[128+o];
  #pragma unroll
  for(int r=0;r<4;r++){
    int node = q*4 + r;
    int n = nb + node;
    float ir = giA[r]+bi0, iz = giB[r]+bi1, inn = giC[r]+bi2;
    float hr = ghA[r]+bh0, hz = ghB[r]+bh1, hn = ghC[r]+bh2;
    float rr  = sigmoidf(ir + hr);
    float z   = sigmoidf(iz + hz);
    float ngv = tanhf(inn + rr*hn);
    float hold = h2f(hhi[node][o]) + h2f(hlo[node][o]);
    float hnew = (1.f - z)*ngv + z*hold;
    if(n < N_NODES){
      outF[(size_t)n*64 + o] = hnew;
      outB[(size_t)n*64 + o] = f2h(hnew);
    }
  }
}

// ---------------- stem head ----------------
__global__ __launch_bounds__(512) void k_stem(const float* __restrict__ outF, const int* __restrict__ sidx,
                                              const float4* __restrict__ s1P, const float* __restrict__ s1b,
                                              const float4* __restrict__ s2P, const float* __restrict__ s2b,
                                              void* __restrict__ dout, const int* __restrict__ flag){
  int grp = threadIdx.x >> 7, t = threadIdx.x & 127;
  int s = blockIdx.x*4 + grp;
  int isf = *flag;
  __shared__ __align__(16) float xs[4][64], hid[4][64];
  int a = sidx[s];
  if(t < 64) xs[grp][t] = outF[(size_t)a*64 + t];
  __syncthreads();
  if(t < 64){
    float acc = s1b[t];
    const float4* xp = (const float4*)xs[grp];
    #pragma unroll 8
    for(int j4=0;j4<16;j4++){
      float4 w = s1P[j4*64+t];
      float4 x = xp[j4];
      acc += w.x*x.x + w.y*x.y + w.z*x.z + w.w*x.w;
    }
    hid[grp][t] = lrelu(acc);
  }
  __syncthreads();
  if(t < 105){
    float acc = s2b[t];
    const float4* hp = (const float4*)hid[grp];
    #pragma unroll 8
    for(int j4=0;j4<16;j4++){
      float4 w = s2P[j4*112+t];
      float4 h = hp[j4];
      acc += w.x*h.x + w.y*h.y + w.z*h.z + w.w*h.w;
    }
    store_out(dout, isf, OUT_STEM + s*105 + t, acc);
  }
}

// ---------------- jbond head ----------------
__global__ __launch_bounds__(512) void k_jbond(const float* __restrict__ outF, const int* __restrict__ jidx,
                                               const float4* __restrict__ j1P, const float* __restrict__ j1b,
                                               const float* __restrict__ j2w, const float* __restrict__ j2b,
                                               void* __restrict__ dout, const int* __restrict__ flag){
  int grp = threadIdx.x >> 7, t = threadIdx.x & 127;
  int jb = blockIdx.x*4 + grp;
  int isf = *flag;
  __shared__ __align__(16) float xs[4][2][64], hid[4][2][64];
  int at = t >> 6, k = t & 63;
  int a = jidx[jb*2 + at];
  xs[grp][at][k] = outF[(size_t)a*64 + k];
  __syncthreads();
  {
    float acc = j1b[k];
    const float4* xp = (const float4*)xs[grp][at];
    #pragma unroll 8
    for(int j4=0;j4<16;j4++){
      float4 w = j1P[j4*64+k];
      float4 x = xp[j4];
      acc += w.x*x.x + w.y*x.y + w.z*x.z + w.w*x.w;
    }
    hid[grp][at][k] = lrelu(acc);
  }
  __syncthreads();
  if(t < 64){
    float p = (hid[grp][0][t] + hid[grp][1][t]) * j2w[t];
    #pragma unroll
    for(int s=32;s;s>>=1) p += __shfl_xor(p, s, 64);
    if(t==0) store_out(dout, isf, OUT_JB + jb, 0.5f*p + j2b[0]);
  }
}

// ---------------- Set2Set + final linear ----------------
__global__ __launch_bounds__(64) void k_s2s(const float* __restrict__ outF, const int* __restrict__ batch,
                                            const float* __restrict__ bih, const float* __restrict__ bhh,
                                            const float* __restrict__ loutw, const float* __restrict__ loutb,
                                            void* __restrict__ dout, const int* __restrict__ flag){
  int b = blockIdx.x, t = threadIdx.x;
  int isf = *flag;
  float i_ = bih[t]     + bhh[t];
  float g_ = bih[128+t] + bhh[128+t];
  float o_ = bih[192+t] + bhh[192+t];
  float c  = sigmoidf(i_)*tanhf(g_);
  float q  = sigmoidf(o_)*tanhf(c);

  int lo = lower_bound_i(batch, N_NODES, b);
  int hi = lower_bound_i(batch, N_NODES, b+1);

  float emax = -3.4e38f;
  for(int n=lo;n<hi;n++){
    float p = outF[n*64+t]*q;
    #pragma unroll
    for(int s=32;s;s>>=1) p += __shfl_xor(p, s, 64);
    emax = fmaxf(emax, p);
  }
  float Z = 0.f, racc = 0.f;
  for(int n=lo;n<hi;n++){
    float v = outF[n*64+t];
    float p = v*q;
    #pragma unroll
    for(int s=32;s;s>>=1) p += __shfl_xor(p, s, 64);
    float w = expf(p - emax);
    Z += w; racc += w*v;
  }
  float rp = (hi>lo) ? racc/Z : 0.f;

  #pragma unroll
  for(int j=0;j<2;j++){
    float p = q*loutw[j*128+t] + rp*loutw[j*128+64+t];
    #pragma unroll
    for(int s=32;s;s>>=1) p += __shfl_xor(p, s, 64);
    if(t==0) store_out(dout, isf, OUT_FINAL + b*2 + j, p + loutb[j]);
  }
}

extern "C" void kernel_launch(void* const* d_in, const int* in_sizes, int n_in,
                              void* d_out, int out_size, void* d_ws, size_t ws_size,
                              hipStream_t stream) {
  const int* edge_index  = (const int*)d_in[28];
  const int* stem_atmidx = (const int*)d_in[29];
  const int* jbond_atmidx= (const int*)d_in[30];
  const int* batch       = (const int*)d_in[31];

  char* ws = (char*)d_ws;
  size_t off = 0;
  auto alloc = [&](size_t bytes)->void*{ void* p = ws + off; off = (off + bytes + 255) & ~(size_t)255; return p; };

  int*   flag = (int*)  alloc(4);
  float* outF = (float*)alloc((size_t)PADN*64*4);
  u16*   outB = (u16*)  alloc((size_t)PADN*64*2);
  int*   agg  = (int*)  alloc((size_t)PADN*64*4);
  u16*   a1b  = (u16*)  alloc((size_t)N_EDGES*A1S*2);
  u16*   B2b  = (u16*)  alloc((size_t)KCH*2048*2 + 2048*2);   // +1 chunk slack for prefetch tail
  u16*   gBn  = (u16*)  alloc((size_t)NWTILES*4*512*2);       // node-GEMM weights (112 KB)
  float* deg  = (float*)alloc((size_t)PADN*4);
  float4* s1P   = (float4*)alloc(1024*16);
  float4* s2P   = (float4*)alloc(1792*16);
  float4* j1P   = (float4*)alloc(1024*16);

  static const int cvt_idx[N_CVT] = {0,1,2,3,4,5,6,7,8,9,10,11,12,13,14,15,16,17,18,19,20,21,24,25,26,27};
  CvtArgs A;
  float* cF[N_CVT];
  for(int i=0;i<N_CVT;i++){
    int src = cvt_idx[i];
    int n = in_sizes[src];
    cF[i] = (float*)alloc((size_t)n*4);
    A.src[i] = d_in[src];
    A.dst[i] = cF[i];
    A.n[i]   = n;
  }
  (void)ws_size; (void)n_in; (void)out_size;
  float* xF=cF[0];   float* eaF=cF[1];  float* l0w=cF[2];  float* l0b=cF[3];
  float* e1w=cF[4];  float* e1b=cF[5];  float* e2w=cF[6];  float* e2b=cF[7];
  float* rootw=cF[8];float* convb=cF[9];
  float* wih=cF[10]; float* whh=cF[11]; float* bih=cF[12]; float* bhh=cF[13];
  float* s1w=cF[14]; float* s1b=cF[15]; float* s2w=cF[16]; float* s2b=cF[17];
  float* j1w=cF[18]; float* j1b=cF[19]; float* j2w=cF[20]; float* j2b=cF[21];
  float* lbih=cF[22];float* lbhh=cF[23];float* loutw=cF[24];float* loutb=cF[25];

  hipMemsetAsync(flag, 0, 4, stream);

  k_sniff <<<128, 256, 0, stream>>>((const u16*)d_in[0], in_sizes[0], flag, deg, agg, outF, outB);
  k_cvt   <<<512, 256, 0, stream>>>(A, flag);

  k_lin0    <<<N_NODES, 64, 0, stream>>>(xF, l0w, l0b, outF, outB);
  k_a1      <<<N_EDGES, 128, 0, stream>>>(eaF, e1w, e1b, a1b, edge_index, deg);
  k_packAll <<<PACK_TOTAL/256, 256, 0, stream>>>(e2w, e2b, B2b, rootw, wih, whh, gBn,
                                                 s1w, s2w, j1w, s1P, s2P, j1P);

  for(int it=0; it<6; it++){
    k_egemm<<<EGRIDE, 512, 0, stream>>>(outB, a1b, B2b, edge_index, agg);
    k_node <<<NGROUPS, 256, 0, stream>>>(agg, deg, outF, outB, gBn, convb, bih, bhh);
  }

  k_stem <<<N_STEMS/4, 512, 0, stream>>>(outF, stem_atmidx, s1P, s1b, s2P, s2b, d_out, flag);
  k_jbond<<<N_JBONDS/4, 512, 0, stream>>>(outF, jbond_atmidx, j1P, j1b, j2w, j2b, d_out, flag);
  k_s2s  <<<NUM_GRAPHS, 64, 0, stream>>>(outF, batch, lbih, lbhh, loutw, loutb, d_out, flag);
}